// Round 5
// baseline (2793.096 us; speedup 1.0000x reference)
//
#include <hip/hip_runtime.h>

// Problem constants
#define BATCH   64
#define SEQT    512
#define NIN     512
#define NH      1024
#define NG      4096   // 4*NH

typedef __attribute__((ext_vector_type(8))) short short8;
typedef __attribute__((ext_vector_type(4))) float floatx4;

__device__ __forceinline__ float bf2f(unsigned short u) {
    union { float f; unsigned i; } v; v.i = ((unsigned)u) << 16; return v.f;
}
__device__ __forceinline__ unsigned short f2bf(float f) {
    union { float f; unsigned i; } v; v.f = f;
    unsigned x = v.i;
    unsigned r = (x + 0x7fffu + ((x >> 16) & 1u)) >> 16;  // RNE
    return (unsigned short)r;
}
// fast activations: v_exp_f32 + v_rcp_f32, no libm slow paths.
__device__ __forceinline__ float fsigm(float x) {
    return __builtin_amdgcn_rcpf(1.0f + __expf(-x));
}
__device__ __forceinline__ float ftanh(float x) {
    return 1.0f - 2.0f * __builtin_amdgcn_rcpf(1.0f + __expf(2.0f * x));
}

// ---------------- prep kernels ----------------
__global__ void cvt_bf16(const float* __restrict__ src, unsigned short* __restrict__ dst, long n) {
    long i = (long)blockIdx.x * blockDim.x + threadIdx.x;
    long stride = (long)gridDim.x * blockDim.x;
    for (; i < n; i += stride) dst[i] = f2bf(src[i]);
}

// Rearrange W_hh (4096x1024 fp32) into per-rowgroup bf16 layout with the
// LDS bank-conflict XOR swizzle BAKED IN (consumer reads col c at c^((row&7)<<3)).
__global__ void prep_whh(const float* __restrict__ W, unsigned short* __restrict__ dst) {
    long i = (long)blockIdx.x * blockDim.x + threadIdx.x;
    if (i >= (long)NG * NH) return;
    int cs  = (int)(i & (NH - 1));
    int row = (int)(i >> 10) & 63;
    int rg  = (int)(i >> 16);            // 0..63
    int c   = cs ^ ((row & 7) << 3);
    int g = row >> 4, nl = row & 15;
    long src = ((long)(g * NH + rg * 16 + nl) << 10) + c;
    dst[i] = f2bf(W[src]);
}

// ---------------- precompute GEMM: G = x @ W_ih^T + b_ih + b_hh ----------------
__global__ __launch_bounds__(256) void gemm_ih(const unsigned short* __restrict__ A,
                                               const unsigned short* __restrict__ Wb,
                                               const float* __restrict__ b_ih,
                                               const float* __restrict__ b_hh,
                                               unsigned short* __restrict__ G) {
    __shared__ __align__(16) unsigned short a_lds[128][56];
    __shared__ __align__(16) unsigned short b_lds[128][56];
    const int tid  = threadIdx.x;
    const int lane = tid & 63;
    const int w    = tid >> 6;
    const int wm   = w >> 1, wn = w & 1;
    const int bm   = blockIdx.x, bn = blockIdx.y;

    floatx4 acc[4][4] = {};

    const int row = tid >> 1, seg = tid & 1;
    const unsigned short* gA = A  + ((size_t)(bm * 128 + row)) * NIN + seg * 16;
    const unsigned short* gB = Wb + ((size_t)(bn * 128 + row)) * NIN + seg * 16;

    for (int kt = 0; kt < 16; ++kt) {
        __syncthreads();
        *(uint4*)&a_lds[row][seg * 16]     = *(const uint4*)(gA + kt * 32);
        *(uint4*)&a_lds[row][seg * 16 + 8] = *(const uint4*)(gA + kt * 32 + 8);
        *(uint4*)&b_lds[row][seg * 16]     = *(const uint4*)(gB + kt * 32);
        *(uint4*)&b_lds[row][seg * 16 + 8] = *(const uint4*)(gB + kt * 32 + 8);
        __syncthreads();
        short8 af[4], bf[4];
#pragma unroll
        for (int mt = 0; mt < 4; ++mt)
            af[mt] = *(const short8*)&a_lds[wm * 64 + mt * 16 + (lane & 15)][(lane >> 4) * 8];
#pragma unroll
        for (int nt = 0; nt < 4; ++nt)
            bf[nt] = *(const short8*)&b_lds[wn * 64 + nt * 16 + (lane & 15)][(lane >> 4) * 8];
#pragma unroll
        for (int mt = 0; mt < 4; ++mt)
#pragma unroll
            for (int nt = 0; nt < 4; ++nt)
                acc[mt][nt] = __builtin_amdgcn_mfma_f32_16x16x32_bf16(af[mt], bf[nt], acc[mt][nt], 0, 0, 0);
    }
#pragma unroll
    for (int nt = 0; nt < 4; ++nt) {
        int n = bn * 128 + wn * 64 + nt * 16 + (lane & 15);
        float bias = b_ih[n] + b_hh[n];
#pragma unroll
        for (int mt = 0; mt < 4; ++mt) {
#pragma unroll
            for (int r = 0; r < 4; ++r) {
                int m = bm * 128 + wm * 64 + mt * 16 + (lane >> 4) * 4 + r;  // token
                int b = m >> 9, t = m & 511;
                size_t gi = ((size_t)(t * 64 + b)) * NG + n;
                G[gi] = f2bf(acc[mt][nt][r] + bias);
            }
        }
    }
}

// ---------------- persistent sequential kernel ----------------
// 2-D decomposition: block (bg, rg), bg = blockIdx.x&3 (16 batches),
// rg = blockIdx.x>>2 (16 hidden units = 64 gate rows of W_hh).
//
// ROUND-5 (= round-4 tagged-data + hang insurance):
// Publish quantum = 8B [h0,h1 (bf16 pair) | tag32 = step]. Naturally-aligned
// 8B store is atomic -> value+readiness arrive in one LLC flight.
//  - producer: fire-and-forget scoped stores. NO drain sync, NO flag.
//  - consumer: bulk 32x8B scoped loads, check 32 tags (acc |= hi^t),
//    reload-all on miss. Detection = store flight + <=1 poll period.
// Safety (2-deep parity ping-pong, equality tags): a block publishes t+1
// only after its waves' polls saw tag==t from ALL 64 producers (chunk union)
// and joined at the part-sync => every block finished its t-1-parity reads
// => overwrite safe; a block can't run 2 ahead. Tag progression per quantum
// is monotone t-2 -> t, so equality polls can't be starved.
// HANG INSURANCE (diagnostic): bounded retry (16K ~ 7ms >> any legit wait).
// If a livelock exists the kernel completes with wrong data (visible FAIL)
// instead of killing the container. s_sleep(2) between retries cuts LLC
// poll pressure.
__global__ __launch_bounds__(256, 1) void seq_kernel(const unsigned short* __restrict__ Wp,
                                                     const unsigned short* __restrict__ G,
                                                     unsigned long long* __restrict__ hq,
                                                     float* __restrict__ out) {
    const int tid  = threadIdx.x;
    const int lane = tid & 63;
    const int w    = tid >> 6;
    const int bid  = blockIdx.x;
    const int bg   = bid & 3;        // batch group (16 batches)
    const int rg   = bid >> 2;       // row group (16 hidden, 64 gate rows)

    // W slice 64 rows x 1024, swizzle baked in global layout -> linear copy.
    __shared__ __align__(16) unsigned short w_lds[64 * 1024];
    // cross-wave K-split partials: [wave][m=batch16][n=64] f32, padded to 68
    __shared__ float part[4][16][68];

    {
        const unsigned short* src = Wp + (size_t)rg * 65536;
#pragma unroll 4
        for (int u = 0; u < 32; ++u)
            *(uint4*)&w_lds[u * 2048 + tid * 8] = *(const uint4*)(src + u * 2048 + tid * 8);
    }
    __syncthreads();

    const int cb = tid >> 4;         // batch within group 0..15
    const int nl = tid & 15;         // hidden within block 0..15
    const int b  = bg * 16 + cb;     // global batch
    const int u  = rg * 16 + nl;     // global hidden unit

    float h0 = 0.f, h1 = 0.f, h2 = 0.f, h3 = 0.f;
    float c0 = 0.f, c1 = 0.f, c2 = 0.f, c3 = 0.f;
    float c_read = 0.f;

    const unsigned short* Gp = G + (size_t)b * NG + u;
    float* out_h = out + (size_t)b * SEQT * NH + u;

    // parity bases (in 8B quanta): parity stride 32768 quanta, bg stride 8192
    unsigned long long* hq0 = hq + (size_t)bg * 8192;            // parity 0
    unsigned long long* hq1 = hq + 32768 + (size_t)bg * 8192;    // parity 1

    // producer quantum index (thread-constant; even-nl threads store)
    const int qidx = ((rg >> 1) * 64 + ((rg & 1) * 2 + (nl >> 3)) * 16 + cb) * 4 + ((nl & 7) >> 1);

    const int swz   = (lane & 7) << 3; // row&7 == lane&7 for all nt tiles
    const int brow0 = lane & 15;
    const int kofs  = (lane >> 4) * 8;

    for (int t = 0; t < SEQT; ++t) {
        // prefetch this thread's 4 input-projection gates (HBM) before any wait
        const unsigned short* Gt = Gp + (size_t)t * 64 * NG;
        unsigned short gi_u = Gt[0], gf_u = Gt[1024], gg_u = Gt[2048], go_u = Gt[3072];

        // ---- poll + load: wave w owns K-chunks 8w..8w+7 (producers rg 16w..16w+15)
        const unsigned long long* hp = ((t & 1) ? hq1 : hq0)
                                       + (size_t)w * 2048 + (size_t)lane * 4;
        unsigned long long q[32];
        for (int retry = 0; retry < 16384; ++retry) {
#pragma unroll
            for (int kk = 0; kk < 8; ++kk)
#pragma unroll
                for (int s = 0; s < 4; ++s)
                    q[kk * 4 + s] = __hip_atomic_load(hp + kk * 256 + s,
                                                      __ATOMIC_RELAXED, __HIP_MEMORY_SCOPE_AGENT);
            if (t == 0) break;                 // step 0 consumes zeros
            unsigned acc_t = 0;
#pragma unroll
            for (int i = 0; i < 32; ++i)
                acc_t |= (unsigned)(q[i] >> 32) ^ (unsigned)t;
            if (acc_t == 0) break;             // per-lane divergent retry
            __builtin_amdgcn_s_sleep(2);
        }

        // ---- GEMM: gates[16 x 64] partial over this wave's K-slice
        floatx4 acc[4] = {};
#pragma unroll
        for (int kk = 0; kk < 8; ++kk) {
            union { unsigned uw[4]; short8 v; } au;
#pragma unroll
            for (int s = 0; s < 4; ++s)
                au.uw[s] = (unsigned)q[kk * 4 + s];   // low words = bf16 pairs
            const int cbase = ((w * 8 + kk) * 32 + kofs) ^ swz;
#pragma unroll
            for (int nt = 0; nt < 4; ++nt) {
                short8 bfr = *(const short8*)&w_lds[(nt * 16 + brow0) * 1024 + cbase];
                acc[nt] = __builtin_amdgcn_mfma_f32_16x16x32_bf16(au.v, bfr, acc[nt], 0, 0, 0);
            }
        }
        // D[m][n]: m = (lane>>4)*4 + r (batch), n = nt*16 + (lane&15) (gate row)
#pragma unroll
        for (int nt = 0; nt < 4; ++nt)
#pragma unroll
            for (int r = 0; r < 4; ++r)
                part[w][(lane >> 4) * 4 + r][nt * 16 + (lane & 15)] = acc[nt][r];
        __syncthreads();   // sync1: part visible; joins all 4 waves' polls

        // reduce 4 wave-partials + LSTM cell for (b, u)
        float gi = (part[0][cb][nl]      + part[1][cb][nl])      + (part[2][cb][nl]      + part[3][cb][nl]);
        float gf = (part[0][cb][16 + nl] + part[1][cb][16 + nl]) + (part[2][cb][16 + nl] + part[3][cb][16 + nl]);
        float gg = (part[0][cb][32 + nl] + part[1][cb][32 + nl]) + (part[2][cb][32 + nl] + part[3][cb][32 + nl]);
        float go = (part[0][cb][48 + nl] + part[1][cb][48 + nl]) + (part[2][cb][48 + nl] + part[3][cb][48 + nl]);
        gi += bf2f(gi_u); gf += bf2f(gf_u); gg += bf2f(gg_u); go += bf2f(go_u);

        float c = fsigm(gf) * c_read + fsigm(gi) * ftanh(gg);
        float h = fsigm(go) * ftanh(c);

        // shift ring, compute interpolated read state for step t+1
        h3 = h2; h2 = h1; h1 = h0; h0 = h;
        c3 = c2; c2 = c1; c1 = c0; c0 = c;
        float hr = 0.3125f * h0 + 0.9375f * h1 - 0.3125f * h2 + 0.0625f * h3;
        c_read   = 0.3125f * c0 + 0.9375f * c1 - 0.3125f * c2 + 0.0625f * c3;

        // publish tagged quantum [h0,h1 | tag=t+1]: fire-and-forget scoped store
        {
            unsigned hv = (unsigned)f2bf(hr);
            unsigned p0 = hv | (__shfl_xor(hv, 1) << 16);   // even-nl lane holds pair
            if ((nl & 1) == 0) {
                unsigned long long qv = ((unsigned long long)(unsigned)(t + 1) << 32)
                                        | (unsigned long long)p0;
                __hip_atomic_store(((t & 1) ? hq0 : hq1) + qidx, qv,
                                   __ATOMIC_RELAXED, __HIP_MEMORY_SCOPE_AGENT);
            }
        }

        // HBM output stores (fire-and-forget; acks amortize over next step)
        out_h[(size_t)t * NH] = h;
        if (t == SEQT - 1) {
            float* o2 = out + (size_t)BATCH * SEQT * NH + (size_t)b * 2 * NH;
            o2[u] = h;
            o2[NH + u] = c;
        }

        // sync2: part WAR only (execution join; LDS reads already consumed).
        // Raw s_barrier = NO vmcnt drain -> publish/out stores stay in flight.
        __builtin_amdgcn_sched_barrier(0);
        __builtin_amdgcn_s_barrier();
        __builtin_amdgcn_sched_barrier(0);
    }
}

// ---------------- host ----------------
extern "C" void kernel_launch(void* const* d_in, const int* in_sizes, int n_in,
                              void* d_out, int out_size, void* d_ws, size_t ws_size,
                              hipStream_t stream) {
    const float* x    = (const float*)d_in[0];
    const float* Wih  = (const float*)d_in[1];
    const float* Whh  = (const float*)d_in[2];
    const float* bih  = (const float*)d_in[3];
    const float* bhh  = (const float*)d_in[4];
    float* outp = (float*)d_out;

    char* ws = (char*)d_ws;
    unsigned short* xb    = (unsigned short*)(ws);                 // 33,554,432 B
    unsigned short* wihb  = (unsigned short*)(ws + 33554432);      //  4,194,304 B (dead after gemm_ih)
    unsigned short* whhb  = (unsigned short*)(ws + 37748736);      //  8,388,608 B
    unsigned short* G     = (unsigned short*)(ws + 46137344);      // 268,435,456 B
    // tagged h exchange buffer: 2 parities x 4 bg x 8192 quanta x 8B = 512 KB
    // lives in wihb's region (dead once gemm_ih completes; memset is stream-ordered)
    unsigned long long* hq = (unsigned long long*)(ws + 33554432);

    cvt_bf16<<<4096, 256, 0, stream>>>(x, xb, (long)BATCH * SEQT * NIN);
    cvt_bf16<<<2048, 256, 0, stream>>>(Wih, wihb, (long)NG * NIN);
    prep_whh<<<16384, 256, 0, stream>>>(Whh, whhb);
    gemm_ih<<<dim3(256, 32), 256, 0, stream>>>(xb, wihb, bih, bhh, G);

    // zero tagged buffer AFTER gemm_ih (wihb dead), BEFORE seq_kernel
    hipMemsetAsync(hq, 0, 524288, stream);

    void* args[] = { (void*)&whhb, (void*)&G, (void*)&hq, (void*)&outp };
    hipLaunchCooperativeKernel((void*)seq_kernel, dim3(256), dim3(256), args, 0, stream);
}